// Round 20
// baseline (95.899 us; speedup 1.0000x reference)
//
#include <hip/hip_runtime.h>
#include <hip/hip_bf16.h>
#include <stdint.h>
#include <stddef.h>

// ClusterLayer: q = normalize_rows( 1 / (1 + ||z-c||^2) )
// N=200000 rows, D=256, KC=256 clusters. fp32 in/out; cross-term via bf16 MFMA.
// R19 = R18 (91.2us: R12 structure + frcp + NT stores + folded +1.0) with
// NT 512 -> 768: 3 waves/SIMD instead of 2. R18's counters show no pipe above
// ~35% (LDS 6.1k cyc, VALU 2.7k, MFMA 0.6k of a 17.9k-cyc CU-iter) ->
// dependency-chain-latency regime; the 3rd wave per SIMD fills chain bubbles.
// (R5's null was at ring-2 where all waves stalled on the same A-load wall.)

#define NT 768
#define GRID 256
#define PAIRS (GRID * 6)   // tile-pairs per sweep = 1536
#define D 256
#define KC 256

typedef __attribute__((ext_vector_type(8))) short short8;  // 8 bf16 (4 VGPRs)
typedef __attribute__((ext_vector_type(4))) float f32x4;   // MFMA accumulator

// fast 1-ulp reciprocal (single v_rcp_f32)
__device__ __forceinline__ float frcp(float x) { return __builtin_amdgcn_rcpf(x); }

// fp32 -> bf16, round-to-nearest-even (branch-free) — prep kernels only
__device__ __forceinline__ short f2bf(float f) {
    uint32_t u = __builtin_bit_cast(uint32_t, f);
    u += 0x7FFFu + ((u >> 16) & 1u);
    return (short)(u >> 16);
}

// packed RNE f32x2 -> bf16x2 (emits v_cvt_pk_bf16_f32)
__device__ __forceinline__ unsigned int pk2(float a, float b) {
    __hip_bfloat162 h = __float22bfloat162_rn(make_float2(a, b));
    unsigned int r;
    __builtin_memcpy(&r, &h, 4);
    return r;
}

// csq[k] = ||c_k||^2 ; one wave per cluster row.
__global__ void prep_csq(const float* __restrict__ C, float* __restrict__ csq) {
    const int k = blockIdx.x;
    const int l = threadIdx.x;  // 0..63
    float4 v = *(const float4*)(C + k * D + l * 4);
    float s = v.x * v.x + v.y * v.y + v.z * v.z + v.w * v.w;
#pragma unroll
    for (int off = 32; off > 0; off >>= 1) s += __shfl_down(s, off);
    if (l == 0) csq[k] = s;
}

// Reorder C into MFMA-B fragment order, bf16 (verified R1-R18):
// Bf[((kk*16 + ct)*64 + lane)*8 + e] = bf16( C[(ct*16 + (lane&15))*D + kk*32 + (lane>>4)*8 + e] )
__global__ void prep_reorder(const float* __restrict__ C, unsigned short* __restrict__ Bf) {
    const int kk = blockIdx.x >> 4;   // 0..7
    const int ct = blockIdx.x & 15;   // 0..15
    const int lane = threadIdx.x;     // 0..63
    const int l15 = lane & 15;
    const int lg = lane >> 4;
    const float* src = C + (size_t)(ct * 16 + l15) * D + kk * 32 + lg * 8;
    float4 a0 = *(const float4*)(src);
    float4 a1 = *(const float4*)(src + 4);
    ushort4 p0, p1;
    p0.x = (unsigned short)f2bf(a0.x); p0.y = (unsigned short)f2bf(a0.y);
    p0.z = (unsigned short)f2bf(a0.z); p0.w = (unsigned short)f2bf(a0.w);
    p1.x = (unsigned short)f2bf(a1.x); p1.y = (unsigned short)f2bf(a1.y);
    p1.z = (unsigned short)f2bf(a1.z); p1.w = (unsigned short)f2bf(a1.w);
    unsigned short* dst = Bf + ((size_t)(kk * 16 + ct) * 64 + lane) * 8;
    *(ushort4*)(dst) = p0;
    *(ushort4*)(dst + 4) = p1;
}

__global__ void __launch_bounds__(NT)
main_kernel(const float* __restrict__ z,
            const uint4* __restrict__ Bf,
            const float* __restrict__ csq,
            float* __restrict__ out, int ntiles) {
    __shared__ uint4 ldsB[8192];                       // 128KB fragment-ordered bf16 B
    __shared__ __align__(16) float ldsRS[2][12][16];   // [parity][wave][row] row-sum exchange

    const int tid  = threadIdx.x;
    const int lane = tid & 63;
    const int wave = tid >> 6;           // 0..11
    const int l15  = lane & 15;
    const int lg   = lane >> 4;          // 0..3
    const int half = wave & 1;           // which 128-col half of the tile
    const int pair = wave >> 1;          // tile-pair index within block (0..5)

    // stage whole B once (<=11 x dwordx4 per thread), linear -> conflict-free
#pragma unroll
    for (int i = 0; i < 11; ++i) {
        const int idx = tid + i * NT;
        if (idx < 8192) ldsB[idx] = Bf[idx];
    }
    __syncthreads();

    // 1 + c_sq for this lane's 8 columns (col = half*128 + ct*16 + l15)
    float csqr1[8];
#pragma unroll
    for (int ct = 0; ct < 8; ++ct) csqr1[ct] = 1.0f + csq[half * 128 + ct * 16 + l15];

    const char* ldsb = (const char*)ldsB;
    const int laneoff = (lane << 4) + (half << 13);  // lane*16 + half*8 frag-blocks

    // per-block iteration count (tail-balanced)
    const int niter = (ntiles - blockIdx.x * 6 + PAIRS - 1) / PAIRS;

    int t = blockIdx.x * 6 + pair;                   // < 1536 <= ntiles: initially valid

    const float* zrow = z + (size_t)(t * 16 + l15) * D + lg * 8;
    // 8-deep rolling A ring: S[kk] holds k-step kk of the current tile;
    // consuming S[kk] refills it with the NEXT tile's k-step kk.
    float4 S0[8], S1[8];
#pragma unroll
    for (int s = 0; s < 8; ++s) {
        S0[s] = *(const float4*)(zrow + s * 32);
        S1[s] = *(const float4*)(zrow + s * 32 + 4);
    }

    for (int i = 0; i < niter; ++i) {
        const bool active = t < ntiles;
        const int tn = t + PAIRS;
        const int tnc = (tn < ntiles) ? tn : (ntiles - 1);
        const float* zrow_n = z + (size_t)(tnc * 16 + l15) * D + lg * 8;

        f32x4 acc[8];
        const f32x4 zero4 = {0.f, 0.f, 0.f, 0.f};
#pragma unroll
        for (int ct = 0; ct < 8; ++ct) acc[ct] = zero4;
        float zsq_part = 0.f;

#pragma unroll
        for (int kk = 0; kk < 8; ++kk) {
            // consume slot kk (loaded one full tile ago), refill with next tile
            float4 c0 = S0[kk], c1 = S1[kk];
            const float* pf = zrow_n + kk * 32;
            S0[kk] = *(const float4*)(pf);
            S1[kk] = *(const float4*)(pf + 4);

            zsq_part += c0.x * c0.x + c0.y * c0.y + c0.z * c0.z + c0.w * c0.w +
                        c1.x * c1.x + c1.y * c1.y + c1.z * c1.z + c1.w * c1.w;
            // packed RNE conversion: 4x v_cvt_pk_bf16_f32
            uint4 u;
            u.x = pk2(c0.x, c0.y); u.y = pk2(c0.z, c0.w);
            u.z = pk2(c1.x, c1.y); u.w = pk2(c1.z, c1.w);
            short8 af;
            __builtin_memcpy(&af, &u, 16);
#pragma unroll
            for (int ct = 0; ct < 8; ++ct) {
                // linear per-lane address -> zero bank conflicts
                short8 bf = *(const short8*)(ldsb + laneoff + ((kk * 16 + ct) << 10));
                acc[ct] = __builtin_amdgcn_mfma_f32_16x16x32_bf16(af, bf, acc[ct], 0, 0, 0);
            }
        }
        // ring now holds next tile's k-steps 0..7 (loads may still be in flight)

        // ||z_row||^2: lane holds partial for row l15; sum over the 4 lane-groups
        float zsq = zsq_part;
        zsq += __shfl_xor(zsq, 16);
        zsq += __shfl_xor(zsq, 32);
        float zsqj[4];
#pragma unroll
        for (int j = 0; j < 4; ++j) zsqj[j] = __shfl(zsq, lg * 4 + j);

        // q = rcp(max(1 + dist, 1)); per-lane partial row sums
        float rs[4] = {0.f, 0.f, 0.f, 0.f};
#pragma unroll
        for (int ct = 0; ct < 8; ++ct) {
#pragma unroll
            for (int j = 0; j < 4; ++j) {
                float d1 = zsqj[j] + csqr1[ct] - 2.0f * acc[ct][j];  // 1 + dist
                d1 = fmaxf(d1, 1.0f);                                // clamp dist >= 0
                float qv = frcp(d1);                                 // single v_rcp_f32
                acc[ct][j] = qv;
                rs[j] += qv;
            }
        }
        // reduce over the 16-lane column group -> this wave's 128-col row sums
#pragma unroll
        for (int j = 0; j < 4; ++j) {
            float s = rs[j];
            s += __shfl_xor(s, 1);
            s += __shfl_xor(s, 2);
            s += __shfl_xor(s, 4);
            s += __shfl_xor(s, 8);
            rs[j] = s;
        }
        // exchange with partner wave (other 128 cols), parity double-buffered
        if (l15 == 0) {
            float4 w = {rs[0], rs[1], rs[2], rs[3]};
            *(float4*)&ldsRS[i & 1][wave][lg * 4] = w;
        }
        asm volatile("s_waitcnt lgkmcnt(0)" ::: "memory");
        __builtin_amdgcn_s_barrier();          // raw: vmcnt NOT drained
        __builtin_amdgcn_sched_barrier(0);
        float4 prs = *(const float4*)&ldsRS[i & 1][wave ^ 1][lg * 4];
        float inv[4];
        inv[0] = frcp(rs[0] + prs.x);
        inv[1] = frcp(rs[1] + prs.y);
        inv[2] = frcp(rs[2] + prs.z);
        inv[3] = frcp(rs[3] + prs.w);

        if (active) {
#pragma unroll
            for (int j = 0; j < 4; ++j) {
                float* orow = out + (size_t)(t * 16 + lg * 4 + j) * KC + half * 128 + l15;
#pragma unroll
                for (int ct = 0; ct < 8; ++ct) {
                    // nontemporal: don't write-allocate (out never re-read)
                    __builtin_nontemporal_store(acc[ct][j] * inv[j], &orow[ct * 16]);
                }
            }
        }
        t = tn;
        zrow = zrow_n;
    }
}

extern "C" void kernel_launch(void* const* d_in, const int* in_sizes, int n_in,
                              void* d_out, int out_size, void* d_ws, size_t ws_size,
                              hipStream_t stream) {
    const float* zp = (const float*)d_in[0];
    const float* Cp = (const float*)d_in[1];
    const int N = in_sizes[0] / D;  // 200000
    unsigned short* Bf = (unsigned short*)d_ws;                          // 128KB bf16 frag-ordered
    float* csq = (float*)((char*)d_ws + (size_t)KC * D * sizeof(unsigned short));  // 1KB

    prep_csq<<<KC, 64, 0, stream>>>(Cp, csq);
    prep_reorder<<<128, 64, 0, stream>>>(Cp, Bf);

    const int ntiles = (N + 15) / 16;  // 12500
    main_kernel<<<GRID, NT, 0, stream>>>(zp, (const uint4*)Bf, csq, (float*)d_out, ntiles);
}

// Round 21
// 88.207 us; speedup vs baseline: 1.0872x; 1.0872x over previous
//
#include <hip/hip_runtime.h>
#include <hip/hip_bf16.h>
#include <stdint.h>
#include <stddef.h>

// ClusterLayer: q = normalize_rows( 1 / (1 + ||z-c||^2) )
// N=200000 rows, D=256, KC=256 clusters. fp32 in/out; cross-term via bf16 MFMA.
// R20 = R18 (91.2us best: R12 structure + frcp + NT stores + folded +1.0) with
// the block-wide per-tile s_barrier replaced by a PAIR-LOCAL LDS flag
// handshake. The rs exchange is only between wave and wave^1; the block
// barrier forced all 4 pairs to wait for the slowest tile each iter. With z
// half L3-resident / half HBM-resident, per-tile latency jitter is ~200 vs
// ~900 cyc -> E[max over 4 pairs] >> mean. Pair-local sync decouples pairs
// (R14 tested independence but confounded: it doubled per-wave LDS+MFMA).
// Ordering: monotonic flag i+1, parity double-buffer; a wave's parity-p
// rs-rewrite at iter i+2 is gated by partner's flag set at i+1, which follows
// the partner's iter-i read -> no WAR race.

#define NT 512
#define GRID 256
#define PAIRS (GRID * 4)   // tile-pairs per sweep = 1024
#define D 256
#define KC 256

typedef __attribute__((ext_vector_type(8))) short short8;  // 8 bf16 (4 VGPRs)
typedef __attribute__((ext_vector_type(4))) float f32x4;   // MFMA accumulator

// fast 1-ulp reciprocal (single v_rcp_f32)
__device__ __forceinline__ float frcp(float x) { return __builtin_amdgcn_rcpf(x); }

// fp32 -> bf16, round-to-nearest-even (branch-free) — prep kernels only
__device__ __forceinline__ short f2bf(float f) {
    uint32_t u = __builtin_bit_cast(uint32_t, f);
    u += 0x7FFFu + ((u >> 16) & 1u);
    return (short)(u >> 16);
}

// packed RNE f32x2 -> bf16x2 (emits v_cvt_pk_bf16_f32)
__device__ __forceinline__ unsigned int pk2(float a, float b) {
    __hip_bfloat162 h = __float22bfloat162_rn(make_float2(a, b));
    unsigned int r;
    __builtin_memcpy(&r, &h, 4);
    return r;
}

// csq[k] = ||c_k||^2 ; one wave per cluster row.
__global__ void prep_csq(const float* __restrict__ C, float* __restrict__ csq) {
    const int k = blockIdx.x;
    const int l = threadIdx.x;  // 0..63
    float4 v = *(const float4*)(C + k * D + l * 4);
    float s = v.x * v.x + v.y * v.y + v.z * v.z + v.w * v.w;
#pragma unroll
    for (int off = 32; off > 0; off >>= 1) s += __shfl_down(s, off);
    if (l == 0) csq[k] = s;
}

// Reorder C into MFMA-B fragment order, bf16 (verified R1-R19):
// Bf[((kk*16 + ct)*64 + lane)*8 + e] = bf16( C[(ct*16 + (lane&15))*D + kk*32 + (lane>>4)*8 + e] )
__global__ void prep_reorder(const float* __restrict__ C, unsigned short* __restrict__ Bf) {
    const int kk = blockIdx.x >> 4;   // 0..7
    const int ct = blockIdx.x & 15;   // 0..15
    const int lane = threadIdx.x;     // 0..63
    const int l15 = lane & 15;
    const int lg = lane >> 4;
    const float* src = C + (size_t)(ct * 16 + l15) * D + kk * 32 + lg * 8;
    float4 a0 = *(const float4*)(src);
    float4 a1 = *(const float4*)(src + 4);
    ushort4 p0, p1;
    p0.x = (unsigned short)f2bf(a0.x); p0.y = (unsigned short)f2bf(a0.y);
    p0.z = (unsigned short)f2bf(a0.z); p0.w = (unsigned short)f2bf(a0.w);
    p1.x = (unsigned short)f2bf(a1.x); p1.y = (unsigned short)f2bf(a1.y);
    p1.z = (unsigned short)f2bf(a1.z); p1.w = (unsigned short)f2bf(a1.w);
    unsigned short* dst = Bf + ((size_t)(kk * 16 + ct) * 64 + lane) * 8;
    *(ushort4*)(dst) = p0;
    *(ushort4*)(dst + 4) = p1;
}

__global__ void __launch_bounds__(NT)
main_kernel(const float* __restrict__ z,
            const uint4* __restrict__ Bf,
            const float* __restrict__ csq,
            float* __restrict__ out, int ntiles) {
    __shared__ uint4 ldsB[8192];                       // 128KB fragment-ordered bf16 B
    __shared__ __align__(16) float ldsRS[2][8][16];    // [parity][wave][row] row-sum exchange
    __shared__ int ldsFlag[2][8];                      // [parity][wave] arrival counter

    const int tid  = threadIdx.x;
    const int lane = tid & 63;
    const int wave = tid >> 6;           // 0..7
    const int l15  = lane & 15;
    const int lg   = lane >> 4;          // 0..3
    const int half = wave & 1;           // which 128-col half of the tile
    const int pair = wave >> 1;          // tile-pair index within block (0..3)

    // stage whole B once (16 x dwordx4 per thread) + init flags; only barrier.
#pragma unroll
    for (int i = 0; i < 16; ++i) ldsB[tid + i * NT] = Bf[tid + i * NT];
    if (tid < 16) ((int*)ldsFlag)[tid] = 0;
    __syncthreads();

    // 1 + c_sq for this lane's 8 columns (col = half*128 + ct*16 + l15)
    float csqr1[8];
#pragma unroll
    for (int ct = 0; ct < 8; ++ct) csqr1[ct] = 1.0f + csq[half * 128 + ct * 16 + l15];

    const char* ldsb = (const char*)ldsB;
    const int laneoff = (lane << 4) + (half << 13);  // lane*16 + half*8 frag-blocks

    // per-block iteration count (tail-balanced; both waves of a pair identical)
    const int niter = (ntiles - blockIdx.x * 4 + PAIRS - 1) / PAIRS;

    int t = blockIdx.x * 4 + pair;                   // < 1024 <= ntiles: initially valid

    const float* zrow = z + (size_t)(t * 16 + l15) * D + lg * 8;
    // 8-deep rolling A ring: S[kk] holds k-step kk of the current tile;
    // consuming S[kk] refills it with the NEXT tile's k-step kk.
    float4 S0[8], S1[8];
#pragma unroll
    for (int s = 0; s < 8; ++s) {
        S0[s] = *(const float4*)(zrow + s * 32);
        S1[s] = *(const float4*)(zrow + s * 32 + 4);
    }

    for (int i = 0; i < niter; ++i) {
        const bool active = t < ntiles;
        const int tn = t + PAIRS;
        const int tnc = (tn < ntiles) ? tn : (ntiles - 1);
        const float* zrow_n = z + (size_t)(tnc * 16 + l15) * D + lg * 8;

        f32x4 acc[8];
        const f32x4 zero4 = {0.f, 0.f, 0.f, 0.f};
#pragma unroll
        for (int ct = 0; ct < 8; ++ct) acc[ct] = zero4;
        float zsq_part = 0.f;

#pragma unroll
        for (int kk = 0; kk < 8; ++kk) {
            // consume slot kk (loaded one full tile ago), refill with next tile
            float4 c0 = S0[kk], c1 = S1[kk];
            const float* pf = zrow_n + kk * 32;
            S0[kk] = *(const float4*)(pf);
            S1[kk] = *(const float4*)(pf + 4);

            zsq_part += c0.x * c0.x + c0.y * c0.y + c0.z * c0.z + c0.w * c0.w +
                        c1.x * c1.x + c1.y * c1.y + c1.z * c1.z + c1.w * c1.w;
            // packed RNE conversion: 4x v_cvt_pk_bf16_f32
            uint4 u;
            u.x = pk2(c0.x, c0.y); u.y = pk2(c0.z, c0.w);
            u.z = pk2(c1.x, c1.y); u.w = pk2(c1.z, c1.w);
            short8 af;
            __builtin_memcpy(&af, &u, 16);
#pragma unroll
            for (int ct = 0; ct < 8; ++ct) {
                // linear per-lane address -> zero bank conflicts
                short8 bf = *(const short8*)(ldsb + laneoff + ((kk * 16 + ct) << 10));
                acc[ct] = __builtin_amdgcn_mfma_f32_16x16x32_bf16(af, bf, acc[ct], 0, 0, 0);
            }
        }
        // ring now holds next tile's k-steps 0..7 (loads may still be in flight)

        // ||z_row||^2: lane holds partial for row l15; sum over the 4 lane-groups
        float zsq = zsq_part;
        zsq += __shfl_xor(zsq, 16);
        zsq += __shfl_xor(zsq, 32);
        float zsqj[4];
#pragma unroll
        for (int j = 0; j < 4; ++j) zsqj[j] = __shfl(zsq, lg * 4 + j);

        // q = rcp(max(1 + dist, 1)); per-lane partial row sums
        float rs[4] = {0.f, 0.f, 0.f, 0.f};
#pragma unroll
        for (int ct = 0; ct < 8; ++ct) {
#pragma unroll
            for (int j = 0; j < 4; ++j) {
                float d1 = zsqj[j] + csqr1[ct] - 2.0f * acc[ct][j];  // 1 + dist
                d1 = fmaxf(d1, 1.0f);                                // clamp dist >= 0
                float qv = frcp(d1);                                 // single v_rcp_f32
                acc[ct][j] = qv;
                rs[j] += qv;
            }
        }
        // reduce over the 16-lane column group -> this wave's 128-col row sums
#pragma unroll
        for (int j = 0; j < 4; ++j) {
            float s = rs[j];
            s += __shfl_xor(s, 1);
            s += __shfl_xor(s, 2);
            s += __shfl_xor(s, 4);
            s += __shfl_xor(s, 8);
            rs[j] = s;
        }
        // exchange with partner wave (other 128 cols): PAIR-LOCAL handshake
        if (l15 == 0) {
            float4 w = {rs[0], rs[1], rs[2], rs[3]};
            *(float4*)&ldsRS[i & 1][wave][lg * 4] = w;
        }
        asm volatile("s_waitcnt lgkmcnt(0)" ::: "memory");  // rs visible before flag
        if (lane == 0)
            __hip_atomic_store(&ldsFlag[i & 1][wave], i + 1,
                               __ATOMIC_RELEASE, __HIP_MEMORY_SCOPE_WORKGROUP);
        while (__hip_atomic_load(&ldsFlag[i & 1][wave ^ 1],
                                 __ATOMIC_ACQUIRE, __HIP_MEMORY_SCOPE_WORKGROUP) < i + 1) {}
        float4 prs = *(const float4*)&ldsRS[i & 1][wave ^ 1][lg * 4];
        float inv[4];
        inv[0] = frcp(rs[0] + prs.x);
        inv[1] = frcp(rs[1] + prs.y);
        inv[2] = frcp(rs[2] + prs.z);
        inv[3] = frcp(rs[3] + prs.w);

        if (active) {
#pragma unroll
            for (int j = 0; j < 4; ++j) {
                float* orow = out + (size_t)(t * 16 + lg * 4 + j) * KC + half * 128 + l15;
#pragma unroll
                for (int ct = 0; ct < 8; ++ct) {
                    // nontemporal: don't write-allocate (out never re-read)
                    __builtin_nontemporal_store(acc[ct][j] * inv[j], &orow[ct * 16]);
                }
            }
        }
        t = tn;
        zrow = zrow_n;
    }
}

extern "C" void kernel_launch(void* const* d_in, const int* in_sizes, int n_in,
                              void* d_out, int out_size, void* d_ws, size_t ws_size,
                              hipStream_t stream) {
    const float* zp = (const float*)d_in[0];
    const float* Cp = (const float*)d_in[1];
    const int N = in_sizes[0] / D;  // 200000
    unsigned short* Bf = (unsigned short*)d_ws;                          // 128KB bf16 frag-ordered
    float* csq = (float*)((char*)d_ws + (size_t)KC * D * sizeof(unsigned short));  // 1KB

    prep_csq<<<KC, 64, 0, stream>>>(Cp, csq);
    prep_reorder<<<128, 64, 0, stream>>>(Cp, Bf);

    const int ntiles = (N + 15) / 16;  // 12500
    main_kernel<<<GRID, NT, 0, stream>>>(zp, (const uint4*)Bf, csq, (float*)d_out, ntiles);
}

// Round 23
// 88.010 us; speedup vs baseline: 1.0896x; 1.0022x over previous
//
#include <hip/hip_runtime.h>
#include <hip/hip_bf16.h>
#include <stdint.h>
#include <stddef.h>

// ClusterLayer: q = normalize_rows( 1 / (1 + ||z-c||^2) )
// N=200000 rows, D=256, KC=256 clusters. fp32 in/out; cross-term via bf16 MFMA.
// R22 = R20 verbatim (best verified: 88.2us). R21's 2-stage pipeline with dual
// asm-"+a" acc arrays failed correctness (absmax 0.125) and the asm-pinned
// path was consistently slower anyway (R14/R15/R16) -> restored known-good.
// Structure: LDS-resident fragment-ordered B (staged once), pair-of-waves per
// 16-row tile (acc[8] via intrinsic MFMA, compiler AGPR placement), 8-deep
// cross-tile rolling A ring, frcp (v_rcp_f32) for all divides, folded +1.0,
// nontemporal stores, PAIR-LOCAL LDS flag handshake (no block barrier).

#define NT 512
#define GRID 256
#define PAIRS (GRID * 4)   // tile-pairs per sweep = 1024
#define D 256
#define KC 256

typedef __attribute__((ext_vector_type(8))) short short8;  // 8 bf16 (4 VGPRs)
typedef __attribute__((ext_vector_type(4))) float f32x4;   // MFMA accumulator

// fast 1-ulp reciprocal (single v_rcp_f32)
__device__ __forceinline__ float frcp(float x) { return __builtin_amdgcn_rcpf(x); }

// fp32 -> bf16, round-to-nearest-even (branch-free) — prep kernels only
__device__ __forceinline__ short f2bf(float f) {
    uint32_t u = __builtin_bit_cast(uint32_t, f);
    u += 0x7FFFu + ((u >> 16) & 1u);
    return (short)(u >> 16);
}

// packed RNE f32x2 -> bf16x2 (emits v_cvt_pk_bf16_f32)
__device__ __forceinline__ unsigned int pk2(float a, float b) {
    __hip_bfloat162 h = __float22bfloat162_rn(make_float2(a, b));
    unsigned int r;
    __builtin_memcpy(&r, &h, 4);
    return r;
}

// csq[k] = ||c_k||^2 ; one wave per cluster row.
__global__ void prep_csq(const float* __restrict__ C, float* __restrict__ csq) {
    const int k = blockIdx.x;
    const int l = threadIdx.x;  // 0..63
    float4 v = *(const float4*)(C + k * D + l * 4);
    float s = v.x * v.x + v.y * v.y + v.z * v.z + v.w * v.w;
#pragma unroll
    for (int off = 32; off > 0; off >>= 1) s += __shfl_down(s, off);
    if (l == 0) csq[k] = s;
}

// Reorder C into MFMA-B fragment order, bf16 (verified R1-R21):
// Bf[((kk*16 + ct)*64 + lane)*8 + e] = bf16( C[(ct*16 + (lane&15))*D + kk*32 + (lane>>4)*8 + e] )
__global__ void prep_reorder(const float* __restrict__ C, unsigned short* __restrict__ Bf) {
    const int kk = blockIdx.x >> 4;   // 0..7
    const int ct = blockIdx.x & 15;   // 0..15
    const int lane = threadIdx.x;     // 0..63
    const int l15 = lane & 15;
    const int lg = lane >> 4;
    const float* src = C + (size_t)(ct * 16 + l15) * D + kk * 32 + lg * 8;
    float4 a0 = *(const float4*)(src);
    float4 a1 = *(const float4*)(src + 4);
    ushort4 p0, p1;
    p0.x = (unsigned short)f2bf(a0.x); p0.y = (unsigned short)f2bf(a0.y);
    p0.z = (unsigned short)f2bf(a0.z); p0.w = (unsigned short)f2bf(a0.w);
    p1.x = (unsigned short)f2bf(a1.x); p1.y = (unsigned short)f2bf(a1.y);
    p1.z = (unsigned short)f2bf(a1.z); p1.w = (unsigned short)f2bf(a1.w);
    unsigned short* dst = Bf + ((size_t)(kk * 16 + ct) * 64 + lane) * 8;
    *(ushort4*)(dst) = p0;
    *(ushort4*)(dst + 4) = p1;
}

__global__ void __launch_bounds__(NT)
main_kernel(const float* __restrict__ z,
            const uint4* __restrict__ Bf,
            const float* __restrict__ csq,
            float* __restrict__ out, int ntiles) {
    __shared__ uint4 ldsB[8192];                       // 128KB fragment-ordered bf16 B
    __shared__ __align__(16) float ldsRS[2][8][16];    // [parity][wave][row] row-sum exchange
    __shared__ int ldsFlag[2][8];                      // [parity][wave] arrival counter

    const int tid  = threadIdx.x;
    const int lane = tid & 63;
    const int wave = tid >> 6;           // 0..7
    const int l15  = lane & 15;
    const int lg   = lane >> 4;          // 0..3
    const int half = wave & 1;           // which 128-col half of the tile
    const int pair = wave >> 1;          // tile-pair index within block (0..3)

    // stage whole B once (16 x dwordx4 per thread) + init flags; only barrier.
#pragma unroll
    for (int i = 0; i < 16; ++i) ldsB[tid + i * NT] = Bf[tid + i * NT];
    if (tid < 16) ((int*)ldsFlag)[tid] = 0;
    __syncthreads();

    // 1 + c_sq for this lane's 8 columns (col = half*128 + ct*16 + l15)
    float csqr1[8];
#pragma unroll
    for (int ct = 0; ct < 8; ++ct) csqr1[ct] = 1.0f + csq[half * 128 + ct * 16 + l15];

    const char* ldsb = (const char*)ldsB;
    const int laneoff = (lane << 4) + (half << 13);  // lane*16 + half*8 frag-blocks

    // per-block iteration count (tail-balanced; both waves of a pair identical)
    const int niter = (ntiles - blockIdx.x * 4 + PAIRS - 1) / PAIRS;

    int t = blockIdx.x * 4 + pair;                   // < 1024 <= ntiles: initially valid

    const float* zrow = z + (size_t)(t * 16 + l15) * D + lg * 8;
    // 8-deep rolling A ring: S[kk] holds k-step kk of the current tile;
    // consuming S[kk] refills it with the NEXT tile's k-step kk.
    float4 S0[8], S1[8];
#pragma unroll
    for (int s = 0; s < 8; ++s) {
        S0[s] = *(const float4*)(zrow + s * 32);
        S1[s] = *(const float4*)(zrow + s * 32 + 4);
    }

    for (int i = 0; i < niter; ++i) {
        const bool active = t < ntiles;
        const int tn = t + PAIRS;
        const int tnc = (tn < ntiles) ? tn : (ntiles - 1);
        const float* zrow_n = z + (size_t)(tnc * 16 + l15) * D + lg * 8;

        f32x4 acc[8];
        const f32x4 zero4 = {0.f, 0.f, 0.f, 0.f};
#pragma unroll
        for (int ct = 0; ct < 8; ++ct) acc[ct] = zero4;
        float zsq_part = 0.f;

#pragma unroll
        for (int kk = 0; kk < 8; ++kk) {
            // consume slot kk (loaded one full tile ago), refill with next tile
            float4 c0 = S0[kk], c1 = S1[kk];
            const float* pf = zrow_n + kk * 32;
            S0[kk] = *(const float4*)(pf);
            S1[kk] = *(const float4*)(pf + 4);

            zsq_part += c0.x * c0.x + c0.y * c0.y + c0.z * c0.z + c0.w * c0.w +
                        c1.x * c1.x + c1.y * c1.y + c1.z * c1.z + c1.w * c1.w;
            // packed RNE conversion: 4x v_cvt_pk_bf16_f32
            uint4 u;
            u.x = pk2(c0.x, c0.y); u.y = pk2(c0.z, c0.w);
            u.z = pk2(c1.x, c1.y); u.w = pk2(c1.z, c1.w);
            short8 af;
            __builtin_memcpy(&af, &u, 16);
#pragma unroll
            for (int ct = 0; ct < 8; ++ct) {
                // linear per-lane address -> zero bank conflicts
                short8 bf = *(const short8*)(ldsb + laneoff + ((kk * 16 + ct) << 10));
                acc[ct] = __builtin_amdgcn_mfma_f32_16x16x32_bf16(af, bf, acc[ct], 0, 0, 0);
            }
        }
        // ring now holds next tile's k-steps 0..7 (loads may still be in flight)

        // ||z_row||^2: lane holds partial for row l15; sum over the 4 lane-groups
        float zsq = zsq_part;
        zsq += __shfl_xor(zsq, 16);
        zsq += __shfl_xor(zsq, 32);
        float zsqj[4];
#pragma unroll
        for (int j = 0; j < 4; ++j) zsqj[j] = __shfl(zsq, lg * 4 + j);

        // q = rcp(max(1 + dist, 1)); per-lane partial row sums
        float rs[4] = {0.f, 0.f, 0.f, 0.f};
#pragma unroll
        for (int ct = 0; ct < 8; ++ct) {
#pragma unroll
            for (int j = 0; j < 4; ++j) {
                float d1 = zsqj[j] + csqr1[ct] - 2.0f * acc[ct][j];  // 1 + dist
                d1 = fmaxf(d1, 1.0f);                                // clamp dist >= 0
                float qv = frcp(d1);                                 // single v_rcp_f32
                acc[ct][j] = qv;
                rs[j] += qv;
            }
        }
        // reduce over the 16-lane column group -> this wave's 128-col row sums
#pragma unroll
        for (int j = 0; j < 4; ++j) {
            float s = rs[j];
            s += __shfl_xor(s, 1);
            s += __shfl_xor(s, 2);
            s += __shfl_xor(s, 4);
            s += __shfl_xor(s, 8);
            rs[j] = s;
        }
        // exchange with partner wave (other 128 cols): PAIR-LOCAL handshake
        if (l15 == 0) {
            float4 w = {rs[0], rs[1], rs[2], rs[3]};
            *(float4*)&ldsRS[i & 1][wave][lg * 4] = w;
        }
        asm volatile("s_waitcnt lgkmcnt(0)" ::: "memory");  // rs visible before flag
        if (lane == 0)
            __hip_atomic_store(&ldsFlag[i & 1][wave], i + 1,
                               __ATOMIC_RELEASE, __HIP_MEMORY_SCOPE_WORKGROUP);
        while (__hip_atomic_load(&ldsFlag[i & 1][wave ^ 1],
                                 __ATOMIC_ACQUIRE, __HIP_MEMORY_SCOPE_WORKGROUP) < i + 1) {}
        float4 prs = *(const float4*)&ldsRS[i & 1][wave ^ 1][lg * 4];
        float inv[4];
        inv[0] = frcp(rs[0] + prs.x);
        inv[1] = frcp(rs[1] + prs.y);
        inv[2] = frcp(rs[2] + prs.z);
        inv[3] = frcp(rs[3] + prs.w);

        if (active) {
#pragma unroll
            for (int j = 0; j < 4; ++j) {
                float* orow = out + (size_t)(t * 16 + lg * 4 + j) * KC + half * 128 + l15;
#pragma unroll
                for (int ct = 0; ct < 8; ++ct) {
                    // nontemporal: don't write-allocate (out never re-read)
                    __builtin_nontemporal_store(acc[ct][j] * inv[j], &orow[ct * 16]);
                }
            }
        }
        t = tn;
        zrow = zrow_n;
    }
}

extern "C" void kernel_launch(void* const* d_in, const int* in_sizes, int n_in,
                              void* d_out, int out_size, void* d_ws, size_t ws_size,
                              hipStream_t stream) {
    const float* zp = (const float*)d_in[0];
    const float* Cp = (const float*)d_in[1];
    const int N = in_sizes[0] / D;  // 200000
    unsigned short* Bf = (unsigned short*)d_ws;                          // 128KB bf16 frag-ordered
    float* csq = (float*)((char*)d_ws + (size_t)KC * D * sizeof(unsigned short));  // 1KB

    prep_csq<<<KC, 64, 0, stream>>>(Cp, csq);
    prep_reorder<<<128, 64, 0, stream>>>(Cp, Bf);

    const int ntiles = (N + 15) / 16;  // 12500
    main_kernel<<<GRID, NT, 0, stream>>>(zp, (const uint4*)Bf, csq, (float*)d_out, ntiles);
}